// Round 9
// baseline (745.528 us; speedup 1.0000x reference)
//
#include <hip/hip_runtime.h>

#define NEG 0.2f
#define NPB 8   // nodes per bucket (power of 2)

// h = relu(x) @ W, register-blocked 4x4; + zero bucket counters; + wke fold (block 0).
__global__ __launch_bounds__(128) void k_node(
    const float* __restrict__ x, const float* __restrict__ W,
    const float* __restrict__ att_src, const float* __restrict__ att_dst,
    const float* __restrict__ W_edge, const float* __restrict__ att_edge,
    float* __restrict__ hbuf, float* __restrict__ a_src, float* __restrict__ a_dst,
    float* __restrict__ wke, int* __restrict__ bcount, int N, int nbk) {
    __shared__ float xs[128 * 36];
    __shared__ float Wl[128 * 64];
    const int t  = threadIdx.x;

    int gi = blockIdx.x * 128 + t;
    if (gi < nbk) bcount[gi] = 0;
    if (blockIdx.x == 0) {   // wke[h*64+k] = sum_c W_edge[k][h*32+c]*att_edge[h][c]
        int hh = t >> 6, k = t & 63;
        float s = 0.f;
#pragma unroll
        for (int c = 0; c < 32; ++c)
            s += W_edge[k * 64 + hh * 32 + c] * att_edge[hh * 32 + c];
        wke[hh * 64 + k] = s;
    }

    const int tn = t & 7;
    const int tc = t >> 3;
    const int node0 = blockIdx.x * 32;

    for (int j = t; j < 128 * 64; j += 128) Wl[j] = W[j];
    for (int j = t; j < 32 * 128; j += 128) {
        int n = j >> 7, k = j & 127;
        int nn = node0 + n;
        xs[k * 36 + n] = (nn < N) ? fmaxf(x[(size_t)nn * 128 + k], 0.f) : 0.f;
    }
    __syncthreads();

    float4 acc[4] = {{0,0,0,0},{0,0,0,0},{0,0,0,0},{0,0,0,0}};
#pragma unroll 8
    for (int k = 0; k < 128; ++k) {
        const float4 xv = *(const float4*)(xs + k * 36 + 4 * tn);
        const float4 wv = *(const float4*)(Wl + k * 64 + 4 * tc);
        acc[0].x = fmaf(xv.x, wv.x, acc[0].x); acc[0].y = fmaf(xv.x, wv.y, acc[0].y);
        acc[0].z = fmaf(xv.x, wv.z, acc[0].z); acc[0].w = fmaf(xv.x, wv.w, acc[0].w);
        acc[1].x = fmaf(xv.y, wv.x, acc[1].x); acc[1].y = fmaf(xv.y, wv.y, acc[1].y);
        acc[1].z = fmaf(xv.y, wv.z, acc[1].z); acc[1].w = fmaf(xv.y, wv.w, acc[1].w);
        acc[2].x = fmaf(xv.z, wv.x, acc[2].x); acc[2].y = fmaf(xv.z, wv.y, acc[2].y);
        acc[2].z = fmaf(xv.z, wv.z, acc[2].z); acc[2].w = fmaf(xv.z, wv.w, acc[2].w);
        acc[3].x = fmaf(xv.w, wv.x, acc[3].x); acc[3].y = fmaf(xv.w, wv.y, acc[3].y);
        acc[3].z = fmaf(xv.w, wv.z, acc[3].z); acc[3].w = fmaf(xv.w, wv.w, acc[3].w);
    }

#pragma unroll
    for (int n = 0; n < 4; ++n) {
        int nn = node0 + 4 * tn + n;
        if (nn < N) *(float4*)(hbuf + (size_t)nn * 64 + 4 * tc) = acc[n];
    }

    const float4 as4 = *(const float4*)(att_src + 4 * tc);
    const float4 ad4 = *(const float4*)(att_dst + 4 * tc);
    int head = (t >= 64) ? 1 : 0;
#pragma unroll
    for (int n = 0; n < 4; ++n) {
        float vs = acc[n].x * as4.x + acc[n].y * as4.y + acc[n].z * as4.z + acc[n].w * as4.w;
        float vd = acc[n].x * ad4.x + acc[n].y * ad4.y + acc[n].z * ad4.z + acc[n].w * ad4.w;
#pragma unroll
        for (int m = 8; m <= 32; m <<= 1) {
            vs += __shfl_xor(vs, m, 64);
            vd += __shfl_xor(vd, m, 64);
        }
        int nn = node0 + 4 * tn + n;
        if ((t & 63) < 8 && nn < N) {
            a_src[nn * 2 + head] = vs;
            a_dst[nn * 2 + head] = vd;
        }
    }
}

// Bucket histogram: 1 int atomic/edge on 6250 counters (low contention).
__global__ __launch_bounds__(256) void k_cnt(const int* __restrict__ dstI,
                                             int* __restrict__ bcount, long long E) {
    long long i0 = (long long)blockIdx.x * 256 + threadIdx.x;
    long long stride = (long long)gridDim.x * 256;
    for (long long i = i0; i < E; i += stride)
        atomicAdd(&bcount[dstI[i] >> 3], 1);   // NPB=8
}

// Single-block exclusive scan over nbk bucket counts (two-pass, no local arrays).
__global__ __launch_bounds__(256) void k_bscan(const int* __restrict__ bcount,
                                               int* __restrict__ boffs,
                                               int* __restrict__ bcursor, int nbk) {
    __shared__ int ts[256];
    int t = threadIdx.x;
    int K = (nbk + 255) >> 8;
    int base = t * K;
    int s = 0;
    for (int i = 0; i < K; ++i) {
        int idx = base + i;
        s += (idx < nbk) ? bcount[idx] : 0;
    }
    ts[t] = s;
    __syncthreads();
    for (int off = 1; off < 256; off <<= 1) {
        int y = (t >= off) ? ts[t - off] : 0;
        __syncthreads();
        ts[t] += y;
        __syncthreads();
    }
    int run = ts[t] - s;
    for (int i = 0; i < K; ++i) {
        int idx = base + i;
        if (idx < nbk) {
            int v = bcount[idx];
            boffs[idx] = run;
            bcursor[idx] = run;
            run += v;
        }
    }
}

// Stream edge_attr, compute pa (per-thread, LDS wke), scatter 16B payload into buckets.
__global__ __launch_bounds__(256) void k_part(
    const float* __restrict__ edge_attr, const int* __restrict__ srcI,
    const int* __restrict__ dstI, const float* __restrict__ wke,
    int* __restrict__ bcursor, int4* __restrict__ payload, long long E) {
    __shared__ float wkes[128];
    if (threadIdx.x < 128) wkes[threadIdx.x] = wke[threadIdx.x];
    __syncthreads();
    long long i0 = (long long)blockIdx.x * 256 + threadIdx.x;
    long long stride = (long long)gridDim.x * 256;
    for (long long e = i0; e < E; e += stride) {
        const float4* row = (const float4*)(edge_attr + e * 64);
        float pa0 = 0.f, pa1 = 0.f;
#pragma unroll
        for (int k = 0; k < 16; ++k) {
            float4 ea = row[k];
            float4 wa = *(const float4*)(wkes + k * 4);
            float4 wb = *(const float4*)(wkes + 64 + k * 4);
            pa0 += ea.x * wa.x + ea.y * wa.y + ea.z * wa.z + ea.w * wa.w;
            pa1 += ea.x * wb.x + ea.y * wb.y + ea.z * wb.z + ea.w * wb.w;
        }
        int s = srcI[e], d = dstI[e];
        int pos = atomicAdd(&bcursor[d >> 3], 1);
        payload[pos] = make_int4(__float_as_int(pa0), __float_as_int(pa1), s, d);
    }
}

// One wave per bucket of NPB=8 nodes. Accumulate in wave-private LDS (ds_add_f32),
// 4 edges in flight (16 lanes each), finalize self-loop + normalize + bias inline.
__global__ __launch_bounds__(256) void k_bucket(
    const int4* __restrict__ payload, const int* __restrict__ boffs,
    const int* __restrict__ bcount, const float* __restrict__ a_src,
    const float* __restrict__ a_dst, const float* __restrict__ hbuf,
    const float* __restrict__ bias, float* __restrict__ out, int N, int nbk) {
    __shared__ float lds[4 * NPB * 70];   // per wave: 8 nodes x (64 acc + 5 stats + pad)
    int t = threadIdx.x;
    int w = t >> 6, lane = t & 63;
    int g = lane >> 4, c = lane & 15;
    int bk = blockIdx.x * 4 + w;
    if (bk >= nbk) return;
    float* L = lds + w * NPB * 70;
    for (int i = lane; i < NPB * 70; i += 64) L[i] = 0.f;   // wave-private: no barrier

    int beg = boffs[bk], cnt = bcount[bk];
    float bv = bias[lane];

    for (int j = 0; j < cnt; j += 4) {
        int je = j + g;
        bool v = je < cnt;
        int4 pl = payload[beg + (v ? je : 0)];
        float pa0 = __int_as_float(pl.x), pa1 = __int_as_float(pl.y);
        int s = pl.z, d = pl.w;
        int dl = d & (NPB - 1);
        float2 as2 = *(const float2*)(a_src + 2 * (size_t)s);
        float2 ad2 = *(const float2*)(a_dst + 2 * (size_t)d);
        float4 hv = *(const float4*)(hbuf + (size_t)s * 64 + c * 4);
        float l0 = as2.x + ad2.x + pa0; l0 = l0 > 0.f ? l0 : NEG * l0;
        float l1 = as2.y + ad2.y + pa1; l1 = l1 > 0.f ? l1 : NEG * l1;
        float q0 = __expf(l0), q1 = __expf(l1);
        float q = (c < 8) ? q0 : q1;
        if (v) {
            float* ap = L + dl * 70 + c * 4;
            atomicAdd(ap + 0, q * hv.x);
            atomicAdd(ap + 1, q * hv.y);
            atomicAdd(ap + 2, q * hv.z);
            atomicAdd(ap + 3, q * hv.w);
            if (c == 0) {
                float* sp = L + dl * 70 + 64;
                atomicAdd(sp + 0, q0);
                atomicAdd(sp + 1, q1);
                atomicAdd(sp + 2, pa0);
                atomicAdd(sp + 3, pa1);
                atomicAdd(sp + 4, 1.f);
            }
        }
    }

    // finalize the 8 nodes
    for (int nl = 0; nl < NPB; ++nl) {
        int n = bk * NPB + nl;
        if (n >= N) break;
        float accv = L[nl * 70 + lane];
        float den0 = L[nl * 70 + 64], den1 = L[nl * 70 + 65];
        float sae0 = L[nl * 70 + 66], sae1 = L[nl * 70 + 67];
        float dg   = L[nl * 70 + 68];
        float dgm  = dg > 0.f ? dg : 1.f;
        float as0 = a_src[n * 2 + 0], as1 = a_src[n * 2 + 1];
        float ad0 = a_dst[n * 2 + 0], ad1 = a_dst[n * 2 + 1];
        float l0 = as0 + ad0 + sae0 / dgm; l0 = l0 > 0.f ? l0 : NEG * l0;
        float l1 = as1 + ad1 + sae1 / dgm; l1 = l1 > 0.f ? l1 : NEG * l1;
        float pl0 = __expf(l0), pl1 = __expf(l1);
        float hn = hbuf[(size_t)n * 64 + lane];
        float plx = (lane < 32) ? pl0 : pl1;
        float den = ((lane < 32) ? den0 + pl0 : den1 + pl1) + 1e-16f;
        out[(size_t)n * 64 + lane] = (accv + plx * hn) / den + bv;
    }
}

extern "C" void kernel_launch(void* const* d_in, const int* in_sizes, int n_in,
                              void* d_out, int out_size, void* d_ws, size_t ws_size,
                              hipStream_t stream) {
    const float* x         = (const float*)d_in[0];
    const int*   ei        = (const int*)d_in[1];
    const float* edge_attr = (const float*)d_in[2];
    const float* W         = (const float*)d_in[3];
    const float* W_edge    = (const float*)d_in[4];
    const float* att_src   = (const float*)d_in[5];
    const float* att_dst   = (const float*)d_in[6];
    const float* att_edge  = (const float*)d_in[7];
    const float* bias      = (const float*)d_in[8];

    int N = in_sizes[0] / 128;
    long long E = in_sizes[1] / 2;
    const int* srcI = ei;
    const int* dstI = ei + E;
    int nbk = (N + NPB - 1) / NPB;

    char* ws = (char*)d_ws;
    int4*  payload = (int4*)ws;                ws += (size_t)E * 16;
    float* hbuf    = (float*)ws;               ws += (size_t)N * 64 * 4;
    float* a_src   = (float*)ws;               ws += (size_t)N * 2 * 4;
    float* a_dst   = (float*)ws;               ws += (size_t)N * 2 * 4;
    float* wke     = (float*)ws;               ws += 128 * 4;
    int*   bcount  = (int*)ws;                 ws += (size_t)nbk * 4;
    int*   boffs   = (int*)ws;                 ws += (size_t)nbk * 4;
    int*   bcursor = (int*)ws;                 ws += (size_t)nbk * 4;

    int nblk_node = (N + 31) / 32;
    k_node<<<nblk_node, 128, 0, stream>>>(x, W, att_src, att_dst, W_edge, att_edge,
                                          hbuf, a_src, a_dst, wke, bcount, N, nbk);
    k_cnt<<<2048, 256, 0, stream>>>(dstI, bcount, E);
    k_bscan<<<1, 256, 0, stream>>>(bcount, boffs, bcursor, nbk);
    k_part<<<2048, 256, 0, stream>>>(edge_attr, srcI, dstI, wke, bcursor, payload, E);
    k_bucket<<<(nbk + 3) / 4, 256, 0, stream>>>(payload, boffs, bcount, a_src, a_dst,
                                                hbuf, bias, (float*)d_out, N, nbk);
}

// Round 10
// 536.247 us; speedup vs baseline: 1.3903x; 1.3903x over previous
//
#include <hip/hip_runtime.h>

#define NEG 0.2f

// Zero-fill for count.
__global__ __launch_bounds__(256) void k_zero(int* __restrict__ p, int n) {
    int i = blockIdx.x * 256 + threadIdx.x;
    if (i < n) p[i] = 0;
}

// h = relu(x) @ W, register-blocked 4x4 (R7 version).
__global__ __launch_bounds__(128) void k_node(
    const float* __restrict__ x, const float* __restrict__ W,
    const float* __restrict__ att_src, const float* __restrict__ att_dst,
    float* __restrict__ hbuf, float* __restrict__ a_src, float* __restrict__ a_dst, int N) {
    __shared__ float xs[128 * 36];
    __shared__ float Wl[128 * 64];
    const int t  = threadIdx.x;
    const int tn = t & 7;
    const int tc = t >> 3;
    const int node0 = blockIdx.x * 32;

    for (int j = t; j < 128 * 64; j += 128) Wl[j] = W[j];
    for (int j = t; j < 32 * 128; j += 128) {
        int n = j >> 7, k = j & 127;
        int nn = node0 + n;
        xs[k * 36 + n] = (nn < N) ? fmaxf(x[(size_t)nn * 128 + k], 0.f) : 0.f;
    }
    __syncthreads();

    float4 acc[4] = {{0,0,0,0},{0,0,0,0},{0,0,0,0},{0,0,0,0}};
#pragma unroll 8
    for (int k = 0; k < 128; ++k) {
        const float4 xv = *(const float4*)(xs + k * 36 + 4 * tn);
        const float4 wv = *(const float4*)(Wl + k * 64 + 4 * tc);
        acc[0].x = fmaf(xv.x, wv.x, acc[0].x); acc[0].y = fmaf(xv.x, wv.y, acc[0].y);
        acc[0].z = fmaf(xv.x, wv.z, acc[0].z); acc[0].w = fmaf(xv.x, wv.w, acc[0].w);
        acc[1].x = fmaf(xv.y, wv.x, acc[1].x); acc[1].y = fmaf(xv.y, wv.y, acc[1].y);
        acc[1].z = fmaf(xv.y, wv.z, acc[1].z); acc[1].w = fmaf(xv.y, wv.w, acc[1].w);
        acc[2].x = fmaf(xv.z, wv.x, acc[2].x); acc[2].y = fmaf(xv.z, wv.y, acc[2].y);
        acc[2].z = fmaf(xv.z, wv.z, acc[2].z); acc[2].w = fmaf(xv.z, wv.w, acc[2].w);
        acc[3].x = fmaf(xv.w, wv.x, acc[3].x); acc[3].y = fmaf(xv.w, wv.y, acc[3].y);
        acc[3].z = fmaf(xv.w, wv.z, acc[3].z); acc[3].w = fmaf(xv.w, wv.w, acc[3].w);
    }

#pragma unroll
    for (int n = 0; n < 4; ++n) {
        int nn = node0 + 4 * tn + n;
        if (nn < N) *(float4*)(hbuf + (size_t)nn * 64 + 4 * tc) = acc[n];
    }

    const float4 as4 = *(const float4*)(att_src + 4 * tc);
    const float4 ad4 = *(const float4*)(att_dst + 4 * tc);
    int head = (t >= 64) ? 1 : 0;
#pragma unroll
    for (int n = 0; n < 4; ++n) {
        float vs = acc[n].x * as4.x + acc[n].y * as4.y + acc[n].z * as4.z + acc[n].w * as4.w;
        float vd = acc[n].x * ad4.x + acc[n].y * ad4.y + acc[n].z * ad4.z + acc[n].w * ad4.w;
#pragma unroll
        for (int m = 8; m <= 32; m <<= 1) {
            vs += __shfl_xor(vs, m, 64);
            vd += __shfl_xor(vd, m, 64);
        }
        int nn = node0 + 4 * tn + n;
        if ((t & 63) < 8 && nn < N) {
            a_src[nn * 2 + head] = vs;
            a_dst[nn * 2 + head] = vd;
        }
    }
}

// In-degree histogram (1 int atomic/edge) + wke fold (block 0). Idempotent after k_zero.
__global__ __launch_bounds__(256) void k_hist(
    const int* __restrict__ dstI, int* __restrict__ count, long long E,
    const float* __restrict__ W_edge, const float* __restrict__ att_edge,
    float* __restrict__ wke) {
    if (blockIdx.x == 0 && threadIdx.x < 128) {
        int hh = threadIdx.x >> 6;
        int k  = threadIdx.x & 63;
        float s = 0.f;
#pragma unroll
        for (int c = 0; c < 32; ++c)
            s += W_edge[k * 64 + hh * 32 + c] * att_edge[hh * 32 + c];
        wke[hh * 64 + k] = s;
    }
    long long i0 = (long long)blockIdx.x * 256 + threadIdx.x;
    long long stride = (long long)gridDim.x * 256;
    for (long long i = i0; i < E; i += stride)
        atomicAdd(&count[dstI[i]], 1);
}

// Exclusive scan, 1024 elements per block.
__global__ __launch_bounds__(256) void k_scan1(const int* __restrict__ cnt, int* __restrict__ offs,
                                               int* __restrict__ bsum, int N) {
    __shared__ int ts[256];
    int t = threadIdx.x, blk = blockIdx.x;
    int base = blk * 1024 + t * 4;
    int v[4], s = 0;
#pragma unroll
    for (int i = 0; i < 4; ++i) {
        int idx = base + i;
        v[i] = (idx < N) ? cnt[idx] : 0;
        s += v[i];
    }
    ts[t] = s;
    __syncthreads();
    for (int off = 1; off < 256; off <<= 1) {
        int y = (t >= off) ? ts[t - off] : 0;
        __syncthreads();
        ts[t] += y;
        __syncthreads();
    }
    int run = ts[t] - s;
#pragma unroll
    for (int i = 0; i < 4; ++i) {
        int idx = base + i;
        if (idx < N) offs[idx] = run;
        run += v[i];
    }
    if (t == 255) bsum[blk] = ts[255];
}

__global__ void k_scan2(int* __restrict__ bsum, int nb) {
    int t = threadIdx.x;
    int orig = (t < nb) ? bsum[t] : 0;
    int v = orig;
#pragma unroll
    for (int off = 1; off < 64; off <<= 1) {
        int y = __shfl_up(v, off, 64);
        if (t >= off) v += y;
    }
    if (t < nb) bsum[t] = v - orig;
}

__global__ void k_scan3(int* __restrict__ offs, const int* __restrict__ bsum,
                        int* __restrict__ cursor, int N) {
    int idx = blockIdx.x * 256 + threadIdx.x;
    if (idx < N) {
        int o = offs[idx] + bsum[idx >> 10];
        offs[idx] = o;
        cursor[idx] = o;
    }
}

// CSR scatter of (eid, src) pairs — 8B per edge.
__global__ __launch_bounds__(256) void k_sort(
    const int* __restrict__ srcI, const int* __restrict__ dstI,
    int* __restrict__ cursor, int2* __restrict__ epos, long long E) {
    long long i0 = (long long)blockIdx.x * 256 + threadIdx.x;
    long long stride = (long long)gridDim.x * 256;
    for (long long e = i0; e < E; e += stride) {
        int s = srcI[e], d = dstI[e];
        int pos = atomicAdd(&cursor[d], 1);
        epos[pos] = make_int2((int)e, s);
    }
}

// Pure stream: edge_attr -> pa2[e] (sequential write, no atomics, no scatter).
__global__ __launch_bounds__(256) void k_paseq(
    const float* __restrict__ edge_attr, const float* __restrict__ wke,
    float2* __restrict__ pa2, long long E) {
    __shared__ float wkes[128];
    if (threadIdx.x < 128) wkes[threadIdx.x] = wke[threadIdx.x];
    __syncthreads();
    long long i0 = (long long)blockIdx.x * 256 + threadIdx.x;
    long long stride = (long long)gridDim.x * 256;
    for (long long e = i0; e < E; e += stride) {
        const float4* row = (const float4*)(edge_attr + e * 64);
        float pa0 = 0.f, pa1 = 0.f;
#pragma unroll
        for (int k = 0; k < 16; ++k) {
            float4 ea = row[k];
            float4 wa = *(const float4*)(wkes + k * 4);
            float4 wb = *(const float4*)(wkes + 64 + k * 4);
            pa0 += ea.x * wa.x + ea.y * wa.y + ea.z * wa.z + ea.w * wa.w;
            pa1 += ea.x * wb.x + ea.y * wb.y + ea.z * wb.z + ea.w * wb.w;
        }
        pa2[e] = make_float2(pa0, pa1);
    }
}

// Per-node aggregation: 64 lanes/node, 4-way edge-parallel, pipelined; pa gathered by eid.
__global__ __launch_bounds__(256) void k_agg(
    const int2* __restrict__ epos, const float2* __restrict__ pa2,
    const int* __restrict__ offs, const int* __restrict__ count,
    const float* __restrict__ a_src, const float* __restrict__ a_dst,
    const float* __restrict__ hbuf, const float* __restrict__ bias,
    float* __restrict__ out, int N) {
    int t = threadIdx.x;
    int lane = t & 63;
    int sub = lane & 15;
    int grp = lane >> 4;
    int n = blockIdx.x * 4 + (t >> 6);
    if (n >= N) return;
    int cnt  = count[n];
    int base = offs[n];
    float ad0 = a_dst[n * 2 + 0], ad1 = a_dst[n * 2 + 1];
    float accx = 0.f, accy = 0.f, accz = 0.f, accw = 0.f;
    float den0 = 0.f, den1 = 0.f, sae0 = 0.f, sae1 = 0.f;

    if (cnt > 0) {
        int last = cnt - 1;
        int2 epA = epos[base + (grp < cnt ? grp : last)];
        int2 epB = epos[base + (grp + 4 < cnt ? grp + 4 : last)];
        float2 paA = pa2[epA.x];
        float2 asA = *(const float2*)(a_src + 2 * (size_t)epA.y);
        float4 hvA = *(const float4*)(hbuf + (size_t)epA.y * 64 + sub * 4);
        for (int j = grp; j < cnt; j += 4) {
            int jc = j + 8 < cnt ? j + 8 : last;
            int2 epC = epos[base + jc];
            float2 paB = pa2[epB.x];
            float2 asB = *(const float2*)(a_src + 2 * (size_t)epB.y);
            float4 hvB = *(const float4*)(hbuf + (size_t)epB.y * 64 + sub * 4);
            float l0 = asA.x + ad0 + paA.x; l0 = l0 > 0.f ? l0 : NEG * l0;
            float l1 = asA.y + ad1 + paA.y; l1 = l1 > 0.f ? l1 : NEG * l1;
            float q0 = __expf(l0), q1 = __expf(l1);
            float q = (sub < 8) ? q0 : q1;
            accx = fmaf(q, hvA.x, accx);
            accy = fmaf(q, hvA.y, accy);
            accz = fmaf(q, hvA.z, accz);
            accw = fmaf(q, hvA.w, accw);
            den0 += q0; den1 += q1;
            sae0 += paA.x; sae1 += paA.y;
            epA = epB; paA = paB; asA = asB; hvA = hvB;
            epB = epC;
        }
    }
#define RED2(v) { v += __shfl_xor(v, 16, 64); v += __shfl_xor(v, 32, 64); }
    RED2(accx) RED2(accy) RED2(accz) RED2(accw)
    RED2(den0) RED2(den1) RED2(sae0) RED2(sae1)
#undef RED2

    float dg = (cnt > 0) ? (float)cnt : 1.f;
    float as0 = a_src[n * 2 + 0], as1 = a_src[n * 2 + 1];
    float l0 = as0 + ad0 + sae0 / dg; l0 = l0 > 0.f ? l0 : NEG * l0;
    float l1 = as1 + ad1 + sae1 / dg; l1 = l1 > 0.f ? l1 : NEG * l1;
    float pl0 = __expf(l0), pl1 = __expf(l1);
    const float4 hn = *(const float4*)(hbuf + (size_t)n * 64 + sub * 4);
    float pl  = (sub < 8) ? pl0 : pl1;
    float den = ((sub < 8) ? den0 + pl0 : den1 + pl1) + 1e-16f;
    const float4 bv = *(const float4*)(bias + sub * 4);
    if (grp == 0) {
        float4 o;
        o.x = (accx + pl * hn.x) / den + bv.x;
        o.y = (accy + pl * hn.y) / den + bv.y;
        o.z = (accz + pl * hn.z) / den + bv.z;
        o.w = (accw + pl * hn.w) / den + bv.w;
        *(float4*)(out + (size_t)n * 64 + sub * 4) = o;
    }
}

extern "C" void kernel_launch(void* const* d_in, const int* in_sizes, int n_in,
                              void* d_out, int out_size, void* d_ws, size_t ws_size,
                              hipStream_t stream) {
    const float* x         = (const float*)d_in[0];
    const int*   ei        = (const int*)d_in[1];
    const float* edge_attr = (const float*)d_in[2];
    const float* W         = (const float*)d_in[3];
    const float* W_edge    = (const float*)d_in[4];
    const float* att_src   = (const float*)d_in[5];
    const float* att_dst   = (const float*)d_in[6];
    const float* att_edge  = (const float*)d_in[7];
    const float* bias      = (const float*)d_in[8];

    int N = in_sizes[0] / 128;
    long long E = in_sizes[1] / 2;
    const int* srcI = ei;
    const int* dstI = ei + E;

    char* ws = (char*)d_ws;
    int2*  epos   = (int2*)ws;                 ws += (size_t)E * 8;
    float2* pa2   = (float2*)ws;               ws += (size_t)E * 8;
    float* wke    = (float*)ws;                ws += 128 * 4;
    float* hbuf   = (float*)ws;                ws += (size_t)N * 64 * 4;
    float* a_src  = (float*)ws;                ws += (size_t)N * 2 * 4;
    float* a_dst  = (float*)ws;                ws += (size_t)N * 2 * 4;
    int*   count  = (int*)ws;                  ws += (size_t)N * 4;
    int*   offs   = (int*)ws;                  ws += (size_t)N * 4;
    int*   cursor = (int*)ws;                  ws += (size_t)N * 4;
    int*   bsum   = (int*)ws;                  ws += 64 * 4;

    int nb = (N + 1023) / 1024;

    k_node<<<(N + 31) / 32, 128, 0, stream>>>(x, W, att_src, att_dst, hbuf, a_src, a_dst, N);

    // ---- CSR build, run TWICE (idempotent) for cost attribution ----
    for (int rep = 0; rep < 2; ++rep) {
        k_zero<<<(N + 255) / 256, 256, 0, stream>>>(count, N);
        k_hist<<<2048, 256, 0, stream>>>(dstI, count, E, W_edge, att_edge, wke);
        k_scan1<<<nb, 256, 0, stream>>>(count, offs, bsum, N);
        k_scan2<<<1, 64, 0, stream>>>(bsum, nb);
        k_scan3<<<(N + 255) / 256, 256, 0, stream>>>(offs, bsum, cursor, N);
        k_sort<<<2048, 256, 0, stream>>>(srcI, dstI, cursor, epos, E);
    }

    k_paseq<<<2048, 256, 0, stream>>>(edge_attr, wke, pa2, E);

    k_agg<<<(N + 3) / 4, 256, 0, stream>>>(epos, pa2, offs, count, a_src, a_dst, hbuf,
                                           bias, (float*)d_out, N);
}

// Round 11
// 295.135 us; speedup vs baseline: 2.5261x; 1.8170x over previous
//
#include <hip/hip_runtime.h>

#define NEG 0.2f
#define MST 4096   // edges per multisplit tile

// ---- h = relu(x)@W (4x4 register-blocked) + wke fold + msize zero (block 0) ----
__global__ __launch_bounds__(128) void k_node(
    const float* __restrict__ x, const float* __restrict__ W,
    const float* __restrict__ att_src, const float* __restrict__ att_dst,
    const float* __restrict__ W_edge, const float* __restrict__ att_edge,
    float* __restrict__ hbuf, float* __restrict__ a_src, float* __restrict__ a_dst,
    float* __restrict__ wke, int* __restrict__ msize, int N) {
    __shared__ float xs[128 * 36];
    __shared__ float Wl[128 * 64];
    const int t  = threadIdx.x;

    if (blockIdx.x == 0) {
        msize[t] = 0; msize[t + 128] = 0;
        int hh = t >> 6, k = t & 63;
        float s = 0.f;
#pragma unroll
        for (int c = 0; c < 32; ++c)
            s += W_edge[k * 64 + hh * 32 + c] * att_edge[hh * 32 + c];
        wke[hh * 64 + k] = s;
    }

    const int tn = t & 7;
    const int tc = t >> 3;
    const int node0 = blockIdx.x * 32;

    for (int j = t; j < 128 * 64; j += 128) Wl[j] = W[j];
    for (int j = t; j < 32 * 128; j += 128) {
        int n = j >> 7, k = j & 127;
        int nn = node0 + n;
        xs[k * 36 + n] = (nn < N) ? fmaxf(x[(size_t)nn * 128 + k], 0.f) : 0.f;
    }
    __syncthreads();

    float4 acc[4] = {{0,0,0,0},{0,0,0,0},{0,0,0,0},{0,0,0,0}};
#pragma unroll 8
    for (int k = 0; k < 128; ++k) {
        const float4 xv = *(const float4*)(xs + k * 36 + 4 * tn);
        const float4 wv = *(const float4*)(Wl + k * 64 + 4 * tc);
        acc[0].x = fmaf(xv.x, wv.x, acc[0].x); acc[0].y = fmaf(xv.x, wv.y, acc[0].y);
        acc[0].z = fmaf(xv.x, wv.z, acc[0].z); acc[0].w = fmaf(xv.x, wv.w, acc[0].w);
        acc[1].x = fmaf(xv.y, wv.x, acc[1].x); acc[1].y = fmaf(xv.y, wv.y, acc[1].y);
        acc[1].z = fmaf(xv.y, wv.z, acc[1].z); acc[1].w = fmaf(xv.y, wv.w, acc[1].w);
        acc[2].x = fmaf(xv.z, wv.x, acc[2].x); acc[2].y = fmaf(xv.z, wv.y, acc[2].y);
        acc[2].z = fmaf(xv.z, wv.z, acc[2].z); acc[2].w = fmaf(xv.z, wv.w, acc[2].w);
        acc[3].x = fmaf(xv.w, wv.x, acc[3].x); acc[3].y = fmaf(xv.w, wv.y, acc[3].y);
        acc[3].z = fmaf(xv.w, wv.z, acc[3].z); acc[3].w = fmaf(xv.w, wv.w, acc[3].w);
    }

#pragma unroll
    for (int n = 0; n < 4; ++n) {
        int nn = node0 + 4 * tn + n;
        if (nn < N) *(float4*)(hbuf + (size_t)nn * 64 + 4 * tc) = acc[n];
    }

    const float4 as4 = *(const float4*)(att_src + 4 * tc);
    const float4 ad4 = *(const float4*)(att_dst + 4 * tc);
    int head = (t >= 64) ? 1 : 0;
#pragma unroll
    for (int n = 0; n < 4; ++n) {
        float vs = acc[n].x * as4.x + acc[n].y * as4.y + acc[n].z * as4.z + acc[n].w * as4.w;
        float vd = acc[n].x * ad4.x + acc[n].y * ad4.y + acc[n].z * ad4.z + acc[n].w * ad4.w;
#pragma unroll
        for (int m = 8; m <= 32; m <<= 1) {
            vs += __shfl_xor(vs, m, 64);
            vd += __shfl_xor(vd, m, 64);
        }
        int nn = node0 + 4 * tn + n;
        if ((t & 63) < 8 && nn < N) {
            a_src[nn * 2 + head] = vs;
            a_dst[nn * 2 + head] = vd;
        }
    }
}

// ---- coarse bucket histogram (LDS-privatized; bucket = dst>>8) ----
__global__ __launch_bounds__(256) void k_mhist(const int* __restrict__ dstI,
                                               int* __restrict__ msize, long long E) {
    __shared__ int h[256];
    int t = threadIdx.x;
    h[t] = 0;
    __syncthreads();
    long long i0 = (long long)blockIdx.x * 256 + t;
    long long st = (long long)gridDim.x * 256;
    for (long long i = i0; i < E; i += st)
        atomicAdd(&h[dstI[i] >> 8], 1);
    __syncthreads();
    if (h[t]) atomicAdd(&msize[t], h[t]);
}

// ---- exclusive scan over 256 bucket sizes; init mcursor ----
__global__ void k_mscan(const int* __restrict__ msize, int* __restrict__ mbase,
                        int* __restrict__ mcursor) {
    __shared__ int ts[256];
    int t = threadIdx.x;
    int v = msize[t];
    ts[t] = v;
    __syncthreads();
    for (int off = 1; off < 256; off <<= 1) {
        int y = (t >= off) ? ts[t - off] : 0;
        __syncthreads();
        ts[t] += y;
        __syncthreads();
    }
    int ex = ts[t] - v;
    mbase[t] = ex;
    mcursor[t] = ex;
}

// ---- multisplit: tile of 4096 edges -> eids grouped by coarse bucket, coalesced flush ----
__global__ __launch_bounds__(256) void k_ms1(const int* __restrict__ dstI,
                                             int* __restrict__ mcursor,
                                             int* __restrict__ S, long long E) {
    __shared__ int hist[256], start[256], cur[256], gb[256];
    __shared__ int2 stage[MST];   // (global addr, eid)
    int t = threadIdx.x;
    long long base = (long long)blockIdx.x * MST;
    int d[16];
    hist[t] = 0; cur[t] = 0;
    __syncthreads();
#pragma unroll
    for (int k = 0; k < 16; ++k) {
        long long e = base + k * 256 + t;
        d[k] = (e < E) ? dstI[e] : -1;
        if (d[k] >= 0) atomicAdd(&hist[d[k] >> 8], 1);
    }
    __syncthreads();
    int v = hist[t];
    start[t] = v;
    __syncthreads();
    for (int off = 1; off < 256; off <<= 1) {
        int y = (t >= off) ? start[t - off] : 0;
        __syncthreads();
        start[t] += y;
        __syncthreads();
    }
    start[t] -= v;   // exclusive (own element only)
    int g = 0;
    if (v > 0) g = atomicAdd(&mcursor[t], v);
    gb[t] = g;
    __syncthreads();
#pragma unroll
    for (int k = 0; k < 16; ++k) {
        if (d[k] >= 0) {
            int b = d[k] >> 8;
            int p = atomicAdd(&cur[b], 1);
            stage[start[b] + p] = make_int2(gb[b] + p, (int)(base + k * 256 + t));
        }
    }
    __syncthreads();
    int tot = (int)((E - base < MST) ? (E - base) : MST);
    for (int j = t; j < tot; j += 256) {
        int2 pr = stage[j];
        S[pr.x] = pr.y;   // consecutive j in a bucket -> consecutive addresses
    }
}

// ---- per-bucket exact CSR: LDS node-counts + scan + L2-local scatter ----
__global__ __launch_bounds__(1024) void k_ms2(
    const int* __restrict__ S, const int* __restrict__ dstI, const int* __restrict__ srcI,
    const int* __restrict__ mbase, const int* __restrict__ msize,
    int* __restrict__ offs, int* __restrict__ count, int2* __restrict__ epos, int N) {
    __shared__ int cnt[256], pref[256], cur[256];
    int b = blockIdx.x;
    int t = threadIdx.x;
    int mstart = mbase[b], mcnt = msize[b];
    if (t < 256) cnt[t] = 0;
    __syncthreads();
    for (int i = t; i < mcnt; i += 1024) {
        int eid = S[mstart + i];
        atomicAdd(&cnt[dstI[eid] & 255], 1);
    }
    __syncthreads();
    if (t < 256) pref[t] = cnt[t];
    __syncthreads();
    for (int off = 1; off < 256; off <<= 1) {
        int y = 0;
        if (t < 256 && t >= off) y = pref[t - off];
        __syncthreads();
        if (t < 256) pref[t] += y;
        __syncthreads();
    }
    if (t < 256) {
        pref[t] -= cnt[t];   // exclusive
        int node = (b << 8) + t;
        if (node < N) {
            offs[node]  = mstart + pref[t];
            count[node] = cnt[t];
        }
        cur[t] = 0;
    }
    __syncthreads();
    for (int i = t; i < mcnt; i += 1024) {
        int eid = S[mstart + i];
        int l = dstI[eid] & 255;
        int p = atomicAdd(&cur[l], 1);
        epos[mstart + pref[l] + p] = make_int2(eid, srcI[eid]);   // ~51KB window: L2-hit
    }
}

// ---- pure stream: edge_attr -> pa2[e] ----
__global__ __launch_bounds__(256) void k_paseq(
    const float* __restrict__ edge_attr, const float* __restrict__ wke,
    float2* __restrict__ pa2, long long E) {
    __shared__ float wkes[128];
    if (threadIdx.x < 128) wkes[threadIdx.x] = wke[threadIdx.x];
    __syncthreads();
    long long i0 = (long long)blockIdx.x * 256 + threadIdx.x;
    long long stride = (long long)gridDim.x * 256;
    for (long long e = i0; e < E; e += stride) {
        const float4* row = (const float4*)(edge_attr + e * 64);
        float pa0 = 0.f, pa1 = 0.f;
#pragma unroll
        for (int k = 0; k < 16; ++k) {
            float4 ea = row[k];
            float4 wa = *(const float4*)(wkes + k * 4);
            float4 wb = *(const float4*)(wkes + 64 + k * 4);
            pa0 += ea.x * wa.x + ea.y * wa.y + ea.z * wa.z + ea.w * wa.w;
            pa1 += ea.x * wb.x + ea.y * wb.y + ea.z * wb.z + ea.w * wb.w;
        }
        pa2[e] = make_float2(pa0, pa1);
    }
}

// ---- per-node aggregation (R10 version) ----
__global__ __launch_bounds__(256) void k_agg(
    const int2* __restrict__ epos, const float2* __restrict__ pa2,
    const int* __restrict__ offs, const int* __restrict__ count,
    const float* __restrict__ a_src, const float* __restrict__ a_dst,
    const float* __restrict__ hbuf, const float* __restrict__ bias,
    float* __restrict__ out, int N) {
    int t = threadIdx.x;
    int lane = t & 63;
    int sub = lane & 15;
    int grp = lane >> 4;
    int n = blockIdx.x * 4 + (t >> 6);
    if (n >= N) return;
    int cnt  = count[n];
    int base = offs[n];
    float ad0 = a_dst[n * 2 + 0], ad1 = a_dst[n * 2 + 1];
    float accx = 0.f, accy = 0.f, accz = 0.f, accw = 0.f;
    float den0 = 0.f, den1 = 0.f, sae0 = 0.f, sae1 = 0.f;

    if (cnt > 0) {
        int last = cnt - 1;
        int2 epA = epos[base + (grp < cnt ? grp : last)];
        int2 epB = epos[base + (grp + 4 < cnt ? grp + 4 : last)];
        float2 paA = pa2[epA.x];
        float2 asA = *(const float2*)(a_src + 2 * (size_t)epA.y);
        float4 hvA = *(const float4*)(hbuf + (size_t)epA.y * 64 + sub * 4);
        for (int j = grp; j < cnt; j += 4) {
            int jc = j + 8 < cnt ? j + 8 : last;
            int2 epC = epos[base + jc];
            float2 paB = pa2[epB.x];
            float2 asB = *(const float2*)(a_src + 2 * (size_t)epB.y);
            float4 hvB = *(const float4*)(hbuf + (size_t)epB.y * 64 + sub * 4);
            float l0 = asA.x + ad0 + paA.x; l0 = l0 > 0.f ? l0 : NEG * l0;
            float l1 = asA.y + ad1 + paA.y; l1 = l1 > 0.f ? l1 : NEG * l1;
            float q0 = __expf(l0), q1 = __expf(l1);
            float q = (sub < 8) ? q0 : q1;
            accx = fmaf(q, hvA.x, accx);
            accy = fmaf(q, hvA.y, accy);
            accz = fmaf(q, hvA.z, accz);
            accw = fmaf(q, hvA.w, accw);
            den0 += q0; den1 += q1;
            sae0 += paA.x; sae1 += paA.y;
            epA = epB; paA = paB; asA = asB; hvA = hvB;
            epB = epC;
        }
    }
#define RED2(v) { v += __shfl_xor(v, 16, 64); v += __shfl_xor(v, 32, 64); }
    RED2(accx) RED2(accy) RED2(accz) RED2(accw)
    RED2(den0) RED2(den1) RED2(sae0) RED2(sae1)
#undef RED2

    float dg = (cnt > 0) ? (float)cnt : 1.f;
    float as0 = a_src[n * 2 + 0], as1 = a_src[n * 2 + 1];
    float l0 = as0 + ad0 + sae0 / dg; l0 = l0 > 0.f ? l0 : NEG * l0;
    float l1 = as1 + ad1 + sae1 / dg; l1 = l1 > 0.f ? l1 : NEG * l1;
    float pl0 = __expf(l0), pl1 = __expf(l1);
    const float4 hn = *(const float4*)(hbuf + (size_t)n * 64 + sub * 4);
    float pl  = (sub < 8) ? pl0 : pl1;
    float den = ((sub < 8) ? den0 + pl0 : den1 + pl1) + 1e-16f;
    const float4 bv = *(const float4*)(bias + sub * 4);
    if (grp == 0) {
        float4 o;
        o.x = (accx + pl * hn.x) / den + bv.x;
        o.y = (accy + pl * hn.y) / den + bv.y;
        o.z = (accz + pl * hn.z) / den + bv.z;
        o.w = (accw + pl * hn.w) / den + bv.w;
        *(float4*)(out + (size_t)n * 64 + sub * 4) = o;
    }
}

extern "C" void kernel_launch(void* const* d_in, const int* in_sizes, int n_in,
                              void* d_out, int out_size, void* d_ws, size_t ws_size,
                              hipStream_t stream) {
    const float* x         = (const float*)d_in[0];
    const int*   ei        = (const int*)d_in[1];
    const float* edge_attr = (const float*)d_in[2];
    const float* W         = (const float*)d_in[3];
    const float* W_edge    = (const float*)d_in[4];
    const float* att_src   = (const float*)d_in[5];
    const float* att_dst   = (const float*)d_in[6];
    const float* att_edge  = (const float*)d_in[7];
    const float* bias      = (const float*)d_in[8];

    int N = in_sizes[0] / 128;
    long long E = in_sizes[1] / 2;
    const int* srcI = ei;
    const int* dstI = ei + E;
    int nbk = (N + 255) >> 8;   // 196 coarse buckets

    char* ws = (char*)d_ws;
    int2*  epos    = (int2*)ws;                ws += (size_t)E * 8;
    float2* pa2    = (float2*)ws;              ws += (size_t)E * 8;
    int*   S       = (int*)ws;                 ws += (size_t)E * 4;
    float* hbuf    = (float*)ws;               ws += (size_t)N * 64 * 4;
    float* a_src   = (float*)ws;               ws += (size_t)N * 2 * 4;
    float* a_dst   = (float*)ws;               ws += (size_t)N * 2 * 4;
    float* wke     = (float*)ws;               ws += 128 * 4;
    int*   offs    = (int*)ws;                 ws += (size_t)N * 4;
    int*   count   = (int*)ws;                 ws += (size_t)N * 4;
    int*   msize   = (int*)ws;                 ws += 256 * 4;
    int*   mbase   = (int*)ws;                 ws += 256 * 4;
    int*   mcursor = (int*)ws;                 ws += 256 * 4;

    k_node<<<(N + 31) / 32, 128, 0, stream>>>(x, W, att_src, att_dst, W_edge, att_edge,
                                              hbuf, a_src, a_dst, wke, msize, N);
    k_mhist<<<1024, 256, 0, stream>>>(dstI, msize, E);
    k_mscan<<<1, 256, 0, stream>>>(msize, mbase, mcursor);

    int ntiles = (int)((E + MST - 1) / MST);
    k_ms1<<<ntiles, 256, 0, stream>>>(dstI, mcursor, S, E);
    k_ms2<<<nbk, 1024, 0, stream>>>(S, dstI, srcI, mbase, msize, offs, count, epos, N);

    k_paseq<<<2048, 256, 0, stream>>>(edge_attr, wke, pa2, E);

    k_agg<<<(N + 3) / 4, 256, 0, stream>>>(epos, pa2, offs, count, a_src, a_dst, hbuf,
                                           bias, (float*)d_out, N);
}